// Round 6
// baseline (427.494 us; speedup 1.0000x reference)
//
#include <hip/hip_runtime.h>
#include <hip/hip_bf16.h>
#include <stdint.h>

#define LN_EPS 1e-5f

typedef float f32x4 __attribute__((ext_vector_type(4)));
typedef short short8 __attribute__((ext_vector_type(8)));

// ---------- helpers ----------
__device__ __forceinline__ float bf2f(unsigned int u) {
  union { unsigned int i; float f; } x; x.i = u << 16; return x.f;
}
// round-to-nearest-even fp32 -> bf16 bits (no NaN inputs here)
__device__ __forceinline__ unsigned short f2bf(float f) {
  unsigned int x = __float_as_uint(f);
  x += 0x7fffu + ((x >> 16) & 1u);
  return (unsigned short)(x >> 16);
}

__device__ __forceinline__ void gload16(const void* g, void* l) {
  __builtin_amdgcn_global_load_lds((const __attribute__((address_space(1))) unsigned int*)g,
                                   (__attribute__((address_space(3))) unsigned int*)l, 16, 0, 0);
}

// stage a 128x64 bf16 tile (row stride ldg elems) into linear LDS [128][64]
__device__ __forceinline__ void stage_tile(const unsigned short* g, int ldg,
                                           unsigned short* lds, int wave, int lane) {
#pragma unroll
  for (int i = 0; i < 4; i++) {
    const int chunk = i * 4 + wave;
    const unsigned short* ga = g + (size_t)(chunk * 8 + (lane >> 3)) * ldg + (lane & 7) * 8;
    gload16(ga, lds + chunk * 512);
  }
}

// ---------- K0: codebook row norms + zero usage ----------
__global__ __launch_bounds__(256) void k0_c2_zero(const float* __restrict__ CB,
                                                  float* __restrict__ C2,
                                                  float* __restrict__ usage) {
  const int g = blockIdx.x * 256 + threadIdx.x;   // 131072 threads
  const int code = g >> 4, l16 = g & 15;
  const float4 v = *(const float4*)&CB[(size_t)code * 64 + (l16 << 2)];
  float s = v.x * v.x + v.y * v.y + v.z * v.z + v.w * v.w;
#pragma unroll
  for (int m = 8; m >= 1; m >>= 1) s += __shfl_xor(s, m, 16);
  if (l16 == 0) C2[code] = s;
  if (g < 8192) usage[g] = 0.f;
}

// ---------- K1: fused encode: h=relu(X@W1+b1); LN(128); z=h@W2+b2 ----------
__global__ __launch_bounds__(256) void k1_encode(const float* __restrict__ X,
                                                 const float* __restrict__ W1,
                                                 const float* __restrict__ B1,
                                                 const float* __restrict__ G1,
                                                 const float* __restrict__ Bn1,
                                                 const float* __restrict__ W2,
                                                 const float* __restrict__ B2,
                                                 float* __restrict__ Z) {
  __shared__ float At[64][20];    // A chunk transposed [k][row], pad 20
  __shared__ float Wc[64][128];   // W1 chunk [k][col]
  __shared__ float Ht[128][20];   // normalized h transposed [col][row]
  const int t = threadIdx.x;
  const int row0 = blockIdx.x << 4;
  const int rg = t >> 6;          // wave id = row group (4 rows each)
  const int r0 = rg << 2;
  const int cg = t & 63;          // 64 col groups x 2 cols
  const int c0 = cg << 1;
  const int lr = t >> 4, lkc = (t & 15) << 2;
  float acc[4][2] = {{0,0},{0,0},{0,0},{0,0}};

  for (int k0 = 0; k0 < 1024; k0 += 64) {
    __syncthreads();
    {  // A chunk: 16 rows x 64 k (transposed store)
      const float4 av = *(const float4*)&X[(size_t)(row0 + lr) * 1024 + k0 + lkc];
      At[lkc + 0][lr] = av.x; At[lkc + 1][lr] = av.y;
      At[lkc + 2][lr] = av.z; At[lkc + 3][lr] = av.w;
    }
    {  // W1 chunk: 64 x 128 linear copy
      const float4* wsrc = (const float4*)&W1[(size_t)k0 * 128];
      float4* wdst = (float4*)&Wc[0][0];
#pragma unroll
      for (int i = 0; i < 8; i++) wdst[t + (i << 8)] = wsrc[t + (i << 8)];
    }
    __syncthreads();
#pragma unroll
    for (int kk = 0; kk < 64; kk++) {
      const float4 a = *(const float4*)&At[kk][r0];   // broadcast within wave
      const float2 w = *(const float2*)&Wc[kk][c0];
      acc[0][0] = fmaf(a.x, w.x, acc[0][0]); acc[0][1] = fmaf(a.x, w.y, acc[0][1]);
      acc[1][0] = fmaf(a.y, w.x, acc[1][0]); acc[1][1] = fmaf(a.y, w.y, acc[1][1]);
      acc[2][0] = fmaf(a.z, w.x, acc[2][0]); acc[2][1] = fmaf(a.z, w.y, acc[2][1]);
      acc[3][0] = fmaf(a.w, w.x, acc[3][0]); acc[3][1] = fmaf(a.w, w.y, acc[3][1]);
    }
  }
  const float b1a = B1[c0], b1b = B1[c0 + 1];
  float h[4][2], s1[4], s2[4];
#pragma unroll
  for (int i = 0; i < 4; i++) {
    h[i][0] = fmaxf(acc[i][0] + b1a, 0.f);
    h[i][1] = fmaxf(acc[i][1] + b1b, 0.f);
    s1[i] = h[i][0] + h[i][1];
    s2[i] = h[i][0] * h[i][0] + h[i][1] * h[i][1];
  }
#pragma unroll
  for (int m = 32; m >= 1; m >>= 1) {
#pragma unroll
    for (int i = 0; i < 4; i++) { s1[i] += __shfl_xor(s1[i], m); s2[i] += __shfl_xor(s2[i], m); }
  }
  const float ga = G1[c0], gb = G1[c0 + 1], ba = Bn1[c0], bb = Bn1[c0 + 1];
#pragma unroll
  for (int i = 0; i < 4; i++) {
    const float mean = s1[i] * (1.f / 128.f);
    const float var  = s2[i] * (1.f / 128.f) - mean * mean;
    const float rs = rsqrtf(var + LN_EPS);
    Ht[c0 + 0][r0 + i] = (h[i][0] - mean) * rs * ga + ba;
    Ht[c0 + 1][r0 + i] = (h[i][1] - mean) * rs * gb + bb;
  }
  __syncthreads();
  float za[4] = {0, 0, 0, 0};
  for (int k = 0; k < 128; k++) {
    const float4 hv = *(const float4*)&Ht[k][r0];
    const float wv = W2[(k << 6) + cg];
    za[0] = fmaf(hv.x, wv, za[0]); za[1] = fmaf(hv.y, wv, za[1]);
    za[2] = fmaf(hv.z, wv, za[2]); za[3] = fmaf(hv.w, wv, za[3]);
  }
  const float b2v = B2[cg];
#pragma unroll
  for (int i = 0; i < 4; i++)
    Z[(size_t)(row0 + r0 + i) * 64 + cg] = za[i] + b2v;
}

// ---------- K2: distances + partial argmin ----------
// score = |c|^2 - 2 z.c  (|z|^2 constant per row, drops from argmin)
// grid 1024 = 256 row-blocks x 4 code-quarters. block: 32 rows x 2048 codes,
// 16 chunks of 128 codes. Single-buffer Ct (42 KB total LDS -> 3 blocks/CU,
// 12 waves/CU). Prefetch for chunk c+1 is register-staged and issued right
// after the post-write barrier; its vmcnt-wait lands at the next WR, hidden
// under 64 k-steps of FMA.
__global__ __launch_bounds__(256) void k2_dist(const float* __restrict__ Z,
                                               const float* __restrict__ CB,
                                               const float* __restrict__ C2,
                                               float* __restrict__ Pval,
                                               int* __restrict__ Pidx) {
  __shared__ float Zt[64][34];     // z tile transposed [k][row]  (8.7 KB)
  __shared__ float Ct[64][130];    // codebook chunk transposed   (33.3 KB)
  const int t = threadIdx.x;
  const int lane = t & 63, wave = t >> 6;
  const int rowblk = blockIdx.x >> 2, quarter = blockIdx.x & 3;
  const int row0 = rowblk << 5;       // 32 rows
  const int code0 = quarter << 11;    // 2048 codes per quarter
  const int r0 = (t >> 5) << 2;       // 8 row-groups x 4 rows
  const int c0 = (lane & 31) << 2;    // 32 code-groups x 4 codes

  // stage Zt: 32 rows x 64 k, transposed (once per block)
#pragma unroll
  for (int i = 0; i < 2; i++) {
    const int f = t + (i << 8);
    const int r = f >> 4, kc = (f & 15) << 2;
    const float4 v = *(const float4*)&Z[(size_t)(row0 + r) * 64 + kc];
    Zt[kc + 0][r] = v.x; Zt[kc + 1][r] = v.y;
    Zt[kc + 2][r] = v.z; Zt[kc + 3][r] = v.w;
  }

  // staging assignment per (cr in 0..1, r in 0..3):
  //   code  = cr*64 + wave*16 + (lane>>2)   [16 consecutive codes per wave]
  //   kbase = 4*(lane&3) + 16*r             [4 lanes cover one 64B line]
  // global: fully line-coalesced; transposed LDS store: 2-way (free)
  const int wq = (wave << 4) + (lane >> 2);   // 0..63
  const int kb = (lane & 3) << 2;             // 0,4,8,12
  float4 st[8];
#define K2_PF(cr, r) \
  st[(cr) * 4 + (r)] = *(const float4*)&CB[(size_t)(code0 + chunk * 128 + (cr) * 64 + wq) * 64 + kb + 16 * (r)];
#define K2_WR(cr, r) { \
    const float4 v = st[(cr) * 4 + (r)]; \
    const int k2r = kb + 16 * (r); const int col = (cr) * 64 + wq; \
    Ct[k2r + 0][col] = v.x; Ct[k2r + 1][col] = v.y; \
    Ct[k2r + 2][col] = v.z; Ct[k2r + 3][col] = v.w; }

  {  // prefetch chunk 0
    const int chunk = 0;
    K2_PF(0, 0) K2_PF(0, 1) K2_PF(0, 2) K2_PF(0, 3)
    K2_PF(1, 0) K2_PF(1, 1) K2_PF(1, 2) K2_PF(1, 3)
  }
  __syncthreads();   // Zt visible; Ct has no readers yet

  float minv[4] = {3.4e38f, 3.4e38f, 3.4e38f, 3.4e38f};
  int   mini[4] = {0, 0, 0, 0};

  for (int c = 0; c < 16; c++) {
    // write staged regs -> Ct (vmcnt wait for st happens here)
    K2_WR(0, 0) K2_WR(0, 1) K2_WR(0, 2) K2_WR(0, 3)
    K2_WR(1, 0) K2_WR(1, 1) K2_WR(1, 2) K2_WR(1, 3)
    __syncthreads();
    if (c + 1 < 16) {   // prefetch next chunk (overlaps compute below)
      const int chunk = c + 1;
      K2_PF(0, 0) K2_PF(0, 1) K2_PF(0, 2) K2_PF(0, 3)
      K2_PF(1, 0) K2_PF(1, 1) K2_PF(1, 2) K2_PF(1, 3)
    }
    float acc[4][4];
#pragma unroll
    for (int i = 0; i < 4; i++)
#pragma unroll
      for (int j = 0; j < 4; j++) acc[i][j] = 0.f;
#pragma unroll 4
    for (int k = 0; k < 64; k++) {
      const float4 zv = *(const float4*)&Zt[k][r0];    // broadcast per half-wave
      const float4 cv = *(const float4*)&Ct[k][c0];
      acc[0][0] = fmaf(zv.x, cv.x, acc[0][0]); acc[0][1] = fmaf(zv.x, cv.y, acc[0][1]);
      acc[0][2] = fmaf(zv.x, cv.z, acc[0][2]); acc[0][3] = fmaf(zv.x, cv.w, acc[0][3]);
      acc[1][0] = fmaf(zv.y, cv.x, acc[1][0]); acc[1][1] = fmaf(zv.y, cv.y, acc[1][1]);
      acc[1][2] = fmaf(zv.y, cv.z, acc[1][2]); acc[1][3] = fmaf(zv.y, cv.w, acc[1][3]);
      acc[2][0] = fmaf(zv.z, cv.x, acc[2][0]); acc[2][1] = fmaf(zv.z, cv.y, acc[2][1]);
      acc[2][2] = fmaf(zv.z, cv.z, acc[2][2]); acc[2][3] = fmaf(zv.z, cv.w, acc[2][3]);
      acc[3][0] = fmaf(zv.w, cv.x, acc[3][0]); acc[3][1] = fmaf(zv.w, cv.y, acc[3][1]);
      acc[3][2] = fmaf(zv.w, cv.z, acc[3][2]); acc[3][3] = fmaf(zv.w, cv.w, acc[3][3]);
    }
    // per-chunk min update
    const int codeb = code0 + (c << 7) + c0;
    const float4 c2v = *(const float4*)&C2[codeb];
    const float c2a[4] = {c2v.x, c2v.y, c2v.z, c2v.w};
#pragma unroll
    for (int i = 0; i < 4; i++)
#pragma unroll
      for (int j = 0; j < 4; j++) {
        const float s = fmaf(-2.f, acc[i][j], c2a[j]);
        if (s < minv[i]) { minv[i] = s; mini[i] = codeb + j; }
      }
    __syncthreads();   // all reads of Ct done before next WR
  }
#undef K2_PF
#undef K2_WR
  // argmin reduce across the 32 lanes of each half (xor<=16 stays in half)
#pragma unroll
  for (int m = 16; m >= 1; m >>= 1) {
#pragma unroll
    for (int i = 0; i < 4; i++) {
      const float ov = __shfl_xor(minv[i], m);
      const int   oi = __shfl_xor(mini[i], m);
      if (ov < minv[i] || (ov == minv[i] && oi < mini[i])) { minv[i] = ov; mini[i] = oi; }
    }
  }
  if ((lane & 31) == 0) {
#pragma unroll
    for (int i = 0; i < 4; i++) {
      const int r = row0 + r0 + i;
      Pval[r * 4 + quarter] = minv[i];
      Pidx[r * 4 + quarter] = mini[i];
    }
  }
}

// ---------- K2m: merge the four code-quarter partials ----------
__global__ __launch_bounds__(256) void k2_merge(const float* __restrict__ Pval,
                                                const int* __restrict__ Pidx,
                                                int* __restrict__ IDX,
                                                float* __restrict__ outIdx,
                                                float* __restrict__ usage) {
  const int r = blockIdx.x * 256 + threadIdx.x;   // 8192 threads
  const float4 v = *(const float4*)&Pval[r * 4];
  const int4   i = *(const int4*)&Pidx[r * 4];
  float bv = v.x; int bi = i.x;                    // quarter-major order keeps
  if (v.y < bv) { bv = v.y; bi = i.y; }            // first-occurrence tie-break
  if (v.z < bv) { bv = v.z; bi = i.z; }
  if (v.w < bv) { bv = v.w; bi = i.w; }
  IDX[r] = bi;
  outIdx[r] = (float)bi;
  atomicAdd(&usage[bi], 1.0f);
}

// ---------- transpose + cast fp32 [R][C] -> bf16 [C][R] ----------
__global__ __launch_bounds__(256) void k_tcast(const float* __restrict__ src,
                                               unsigned short* __restrict__ dst,
                                               int R, int C) {
  __shared__ float T[32][33];
  const int tilesC = C >> 5;
  const int bx = blockIdx.x;
  const int tr = bx / tilesC, tc = bx - tr * tilesC;
  const int t = threadIdx.x;
  {
    const int r = t >> 3, c4 = (t & 7) << 2;
    const float4 v = *(const float4*)&src[(size_t)(tr * 32 + r) * C + tc * 32 + c4];
    T[r][c4] = v.x; T[r][c4 + 1] = v.y; T[r][c4 + 2] = v.z; T[r][c4 + 3] = v.w;
  }
  __syncthreads();
  const int c = t >> 3, r4 = (t & 7) << 2;
  ushort4 o;
  o.x = f2bf(T[r4 + 0][c]); o.y = f2bf(T[r4 + 1][c]);
  o.z = f2bf(T[r4 + 2][c]); o.w = f2bf(T[r4 + 3][c]);
  *(ushort4*)&dst[(size_t)(tc * 32 + c) * R + tr * 32 + r4] = o;
}

// ---------- K3: gather codebook rows by index, cast to bf16 ----------
__global__ __launch_bounds__(256) void k3_gather(const float* __restrict__ CB,
                                                 const int* __restrict__ IDX,
                                                 unsigned short* __restrict__ SEL) {
  const int g = blockIdx.x * 256 + threadIdx.x;  // 131072 threads
  const int row = g >> 4, c4 = (g & 15) << 2;
  const int code = IDX[row];
  const float4 v = *(const float4*)&CB[(size_t)code * 64 + c4];
  ushort4 o;
  o.x = f2bf(v.x); o.y = f2bf(v.y); o.z = f2bf(v.z); o.w = f2bf(v.w);
  *(ushort4*)&SEL[(size_t)row * 64 + c4] = o;
}

// ---------- K4: h1 = relu(sel @ rec_w1 + b1), bf16 out; M=8192 N=2048 K=64 ----------
__global__ __launch_bounds__(256) void k4_rec1(const unsigned short* __restrict__ A,
                                               const unsigned short* __restrict__ Bt,
                                               const float* __restrict__ bias,
                                               unsigned short* __restrict__ H) {
  __shared__ __align__(16) unsigned short As[128 * 64];
  __shared__ __align__(16) unsigned short Bs[128 * 64];
  const int t = threadIdx.x;
  const int wave = t >> 6, lane = t & 63;
  const int bx = blockIdx.x;
  const int tm = bx >> 4, tn = bx & 15;
  const int m0 = tm << 7, n0 = tn << 7;
  const int wm = wave >> 1, wn = wave & 1;
  const int ln15 = lane & 15, lk = (lane >> 4) << 3;
  stage_tile(A + (size_t)m0 * 64, 64, As, wave, lane);
  stage_tile(Bt + (size_t)n0 * 64, 64, Bs, wave, lane);
  asm volatile("s_waitcnt vmcnt(0)" ::: "memory");
  __syncthreads();
  f32x4 acc[4][4];
#pragma unroll
  for (int i = 0; i < 4; i++)
#pragma unroll
    for (int j = 0; j < 4; j++) acc[i][j] = (f32x4){0.f, 0.f, 0.f, 0.f};
#pragma unroll
  for (int ks = 0; ks < 2; ks++) {
    short8 a[4], b[4];
#pragma unroll
    for (int i = 0; i < 4; i++)
      a[i] = *(const short8*)&As[(wm * 64 + i * 16 + ln15) * 64 + ks * 32 + lk];
#pragma unroll
    for (int j = 0; j < 4; j++)
      b[j] = *(const short8*)&Bs[(wn * 64 + j * 16 + ln15) * 64 + ks * 32 + lk];
#pragma unroll
    for (int i = 0; i < 4; i++)
#pragma unroll
      for (int j = 0; j < 4; j++)
        acc[i][j] = __builtin_amdgcn_mfma_f32_16x16x32_bf16(a[i], b[j], acc[i][j], 0, 0, 0);
  }
  const int l4 = (lane >> 4) << 2;
#pragma unroll
  for (int j = 0; j < 4; j++) {
    const int col = n0 + wn * 64 + j * 16 + ln15;
    const float bv = bias[col];
#pragma unroll
    for (int i = 0; i < 4; i++) {
      const int row = m0 + wm * 64 + i * 16 + l4;
#pragma unroll
      for (int r = 0; r < 4; r++)
        H[(size_t)(row + r) * 2048 + col] = f2bf(fmaxf(acc[i][j][r] + bv, 0.f));
    }
  }
}

// ---------- K5: in-place LayerNorm(2048) on bf16 rows ----------
__global__ __launch_bounds__(256) void k5_ln(unsigned short* __restrict__ H,
                                             const float* __restrict__ G,
                                             const float* __restrict__ B) {
  const int row = blockIdx.x, t = threadIdx.x;
  unsigned short* p = H + (size_t)row * 2048 + t * 8;
  const uint4 raw = *(const uint4*)p;
  float v[8];
  v[0] = bf2f(raw.x & 0xffffu); v[1] = bf2f(raw.x >> 16);
  v[2] = bf2f(raw.y & 0xffffu); v[3] = bf2f(raw.y >> 16);
  v[4] = bf2f(raw.z & 0xffffu); v[5] = bf2f(raw.z >> 16);
  v[6] = bf2f(raw.w & 0xffffu); v[7] = bf2f(raw.w >> 16);
  float s1 = 0.f, s2 = 0.f;
#pragma unroll
  for (int i = 0; i < 8; i++) { s1 += v[i]; s2 = fmaf(v[i], v[i], s2); }
#pragma unroll
  for (int m = 32; m >= 1; m >>= 1) { s1 += __shfl_xor(s1, m); s2 += __shfl_xor(s2, m); }
  __shared__ float red[8];
  const int lane = t & 63, wv = t >> 6;
  if (lane == 0) { red[wv] = s1; red[4 + wv] = s2; }
  __syncthreads();
  s1 = red[0] + red[1] + red[2] + red[3];
  s2 = red[4] + red[5] + red[6] + red[7];
  const float mean = s1 * (1.f / 2048.f);
  const float var  = s2 * (1.f / 2048.f) - mean * mean;
  const float rs = rsqrtf(var + LN_EPS);
  const int c = t * 8;
  unsigned int w0, w1, w2, w3;
  {
    const float o0 = (v[0] - mean) * rs * G[c + 0] + B[c + 0];
    const float o1 = (v[1] - mean) * rs * G[c + 1] + B[c + 1];
    w0 = (unsigned int)f2bf(o0) | ((unsigned int)f2bf(o1) << 16);
  }
  {
    const float o0 = (v[2] - mean) * rs * G[c + 2] + B[c + 2];
    const float o1 = (v[3] - mean) * rs * G[c + 3] + B[c + 3];
    w1 = (unsigned int)f2bf(o0) | ((unsigned int)f2bf(o1) << 16);
  }
  {
    const float o0 = (v[4] - mean) * rs * G[c + 4] + B[c + 4];
    const float o1 = (v[5] - mean) * rs * G[c + 5] + B[c + 5];
    w2 = (unsigned int)f2bf(o0) | ((unsigned int)f2bf(o1) << 16);
  }
  {
    const float o0 = (v[6] - mean) * rs * G[c + 6] + B[c + 6];
    const float o1 = (v[7] - mean) * rs * G[c + 7] + B[c + 7];
    w3 = (unsigned int)f2bf(o0) | ((unsigned int)f2bf(o1) << 16);
  }
  uint4 outw; outw.x = w0; outw.y = w1; outw.z = w2; outw.w = w3;
  *(uint4*)p = outw;
}

// ---------- K6: recon = r @ rec_w2 + b2; M=8192 N=1024 K=2048, fp32 out ----------
// 2-phase double-buffered pipeline (T3-minimal): issue next tile's
// global_load_lds BEFORE computing the current tile; one vmcnt(0)+barrier
// per K-tile. __syncthreads() drains lgkm, so all reads of buf complete
// before the next iteration's stage overwrites it.
__global__ __launch_bounds__(256) void k6_rec2(const unsigned short* __restrict__ A,
                                               const unsigned short* __restrict__ Bt,
                                               const float* __restrict__ bias,
                                               float* __restrict__ C) {
  __shared__ __align__(16) unsigned short As[2][128 * 64];
  __shared__ __align__(16) unsigned short Bs[2][128 * 64];
  const int t = threadIdx.x;
  const int wave = t >> 6, lane = t & 63;
  const int bx = blockIdx.x;
  const int tm = bx >> 3, tn = bx & 7;
  const int m0 = tm << 7, n0 = tn << 7;
  const int wm = wave >> 1, wn = wave & 1;
  const int ln15 = lane & 15, lk = (lane >> 4) << 3;
  f32x4 acc[4][4];
#pragma unroll
  for (int i = 0; i < 4; i++)
#pragma unroll
    for (int j = 0; j < 4; j++) acc[i][j] = (f32x4){0.f, 0.f, 0.f, 0.f};

  // prologue: stage tile 0 into buf 0
  stage_tile(A + (size_t)m0 * 2048, 2048, As[0], wave, lane);
  stage_tile(Bt + (size_t)n0 * 2048, 2048, Bs[0], wave, lane);
  asm volatile("s_waitcnt vmcnt(0)" ::: "memory");
  __syncthreads();

  int cur = 0;
  for (int kt = 0; kt < 32; kt++) {
    if (kt + 1 < 32) {   // issue next tile's loads; they fly under the MFMAs
      const int k0 = (kt + 1) << 6;
      stage_tile(A + (size_t)m0 * 2048 + k0, 2048, As[cur ^ 1], wave, lane);
      stage_tile(Bt + (size_t)n0 * 2048 + k0, 2048, Bs[cur ^ 1], wave, lane);
    }
#pragma unroll
    for (int ks = 0; ks < 2; ks++) {
      short8 a[4], b[4];
#pragma unroll
      for (int i = 0; i < 4; i++)
        a[i] = *(const short8*)&As[cur][(wm * 64 + i * 16 + ln15) * 64 + ks * 32 + lk];
#pragma unroll
      for (int j = 0; j < 4; j++)
        b[j] = *(const short8*)&Bs[cur][(wn * 64 + j * 16 + ln15) * 64 + ks * 32 + lk];
#pragma unroll
      for (int i = 0; i < 4; i++)
#pragma unroll
        for (int j = 0; j < 4; j++)
          acc[i][j] = __builtin_amdgcn_mfma_f32_16x16x32_bf16(a[i], b[j], acc[i][j], 0, 0, 0);
    }
    asm volatile("s_waitcnt vmcnt(0)" ::: "memory");
    __syncthreads();
    cur ^= 1;
  }
  const int l4 = (lane >> 4) << 2;
#pragma unroll
  for (int j = 0; j < 4; j++) {
    const int col = n0 + wn * 64 + j * 16 + ln15;
    const float bv = bias[col];
#pragma unroll
    for (int i = 0; i < 4; i++) {
      const int row = m0 + wm * 64 + i * 16 + l4;
#pragma unroll
      for (int r = 0; r < 4; r++)
        C[(size_t)(row + r) * 1024 + col] = acc[i][j][r] + bv;
    }
  }
}

extern "C" void kernel_launch(void* const* d_in, const int* in_sizes, int n_in,
                              void* d_out, int out_size, void* d_ws, size_t ws_size,
                              hipStream_t stream) {
  (void)in_sizes; (void)n_in; (void)out_size; (void)ws_size;
  const float* features = (const float*)d_in[0];
  const float* codebook = (const float*)d_in[1];
  const float* proj_w1  = (const float*)d_in[2];
  const float* proj_b1  = (const float*)d_in[3];
  const float* ln1_g    = (const float*)d_in[4];
  const float* ln1_b    = (const float*)d_in[5];
  const float* proj_w2  = (const float*)d_in[6];
  const float* proj_b2  = (const float*)d_in[7];
  const float* rec_w1   = (const float*)d_in[8];
  const float* rec_b1   = (const float*)d_in[9];
  const float* ln2_g    = (const float*)d_in[10];
  const float* ln2_b    = (const float*)d_in[11];
  const float* rec_w2   = (const float*)d_in[12];
  const float* rec_b2   = (const float*)d_in[13];

  float* out_recon = (float*)d_out;                    // [8192][1024]
  float* out_idx   = out_recon + (size_t)8192 * 1024;  // [8192] (as float)
  float* out_usage = out_idx + 8192;                   // [8192]

  char* ws = (char*)d_ws;
  float*          c2  = (float*)(ws);                       // 32 KB
  int*            idx = (int*)(ws + 32768);                 // 32 KB
  float*          z   = (float*)(ws + 65536);               // 2 MB
  unsigned short* sel = (unsigned short*)(ws + 2162688);    // 1 MB  bf16
  unsigned short* w1t = (unsigned short*)(ws + 3211264);    // 256 KB bf16 [2048][64]
  unsigned short* w2t = (unsigned short*)(ws + 3473408);    // 4 MB  bf16 [1024][2048]
  unsigned short* h1  = (unsigned short*)(ws + 7667712);    // 32 MB bf16 [8192][2048]
  // argmin partials overlap sel's region (consumed by k2_merge before k3 writes sel)
  float* pval = (float*)(ws + 2162688);                     // 128 KB [8192][4]
  int*   pidx = (int*)(ws + 2162688 + 131072);              // 128 KB [8192][4]

  k0_c2_zero<<<512, 256, 0, stream>>>(codebook, c2, out_usage);
  k1_encode <<<512, 256, 0, stream>>>(features, proj_w1, proj_b1, ln1_g, ln1_b,
                                      proj_w2, proj_b2, z);
  k2_dist   <<<1024, 256, 0, stream>>>(z, codebook, c2, pval, pidx);
  k2_merge  <<<32, 256, 0, stream>>>(pval, pidx, idx, out_idx, out_usage);
  k_tcast   <<<128, 256, 0, stream>>>(rec_w1, w1t, 64, 2048);    // -> [2048][64]
  k_tcast   <<<2048, 256, 0, stream>>>(rec_w2, w2t, 2048, 1024); // -> [1024][2048]
  k3_gather <<<512, 256, 0, stream>>>(codebook, idx, sel);
  k4_rec1   <<<1024, 256, 0, stream>>>(sel, w1t, rec_b1, h1);
  k5_ln     <<<8192, 256, 0, stream>>>(h1, ln2_g, ln2_b);
  k6_rec2   <<<512, 256, 0, stream>>>(h1, w2t, rec_b2, out_recon);
}

// Round 7
// 379.023 us; speedup vs baseline: 1.1279x; 1.1279x over previous
//
#include <hip/hip_runtime.h>
#include <hip/hip_bf16.h>
#include <stdint.h>

#define LN_EPS 1e-5f

typedef float f32x4 __attribute__((ext_vector_type(4)));
typedef short short8 __attribute__((ext_vector_type(8)));

// ---------- helpers ----------
__device__ __forceinline__ float bf2f(unsigned int u) {
  union { unsigned int i; float f; } x; x.i = u << 16; return x.f;
}
// round-to-nearest-even fp32 -> bf16 bits (no NaN inputs here)
__device__ __forceinline__ unsigned short f2bf(float f) {
  unsigned int x = __float_as_uint(f);
  x += 0x7fffu + ((x >> 16) & 1u);
  return (unsigned short)(x >> 16);
}

__device__ __forceinline__ void gload16(const void* g, void* l) {
  __builtin_amdgcn_global_load_lds((const __attribute__((address_space(1))) unsigned int*)g,
                                   (__attribute__((address_space(3))) unsigned int*)l, 16, 0, 0);
}

// stage a 128x64 bf16 tile (row stride ldg elems) into linear LDS [128][64]
__device__ __forceinline__ void stage_tile(const unsigned short* g, int ldg,
                                           unsigned short* lds, int wave, int lane) {
#pragma unroll
  for (int i = 0; i < 4; i++) {
    const int chunk = i * 4 + wave;
    const unsigned short* ga = g + (size_t)(chunk * 8 + (lane >> 3)) * ldg + (lane & 7) * 8;
    gload16(ga, lds + chunk * 512);
  }
}

// ---------- K0: codebook row norms + zero usage ----------
__global__ __launch_bounds__(256) void k0_c2_zero(const float* __restrict__ CB,
                                                  float* __restrict__ C2,
                                                  float* __restrict__ usage) {
  const int g = blockIdx.x * 256 + threadIdx.x;   // 131072 threads
  const int code = g >> 4, l16 = g & 15;
  const float4 v = *(const float4*)&CB[(size_t)code * 64 + (l16 << 2)];
  float s = v.x * v.x + v.y * v.y + v.z * v.z + v.w * v.w;
#pragma unroll
  for (int m = 8; m >= 1; m >>= 1) s += __shfl_xor(s, m, 16);
  if (l16 == 0) C2[code] = s;
  if (g < 8192) usage[g] = 0.f;
}

// ---------- K1: fused encode: h=relu(X@W1+b1); LN(128); z=h@W2+b2 ----------
__global__ __launch_bounds__(256) void k1_encode(const float* __restrict__ X,
                                                 const float* __restrict__ W1,
                                                 const float* __restrict__ B1,
                                                 const float* __restrict__ G1,
                                                 const float* __restrict__ Bn1,
                                                 const float* __restrict__ W2,
                                                 const float* __restrict__ B2,
                                                 float* __restrict__ Z) {
  __shared__ float At[64][20];    // A chunk transposed [k][row], pad 20
  __shared__ float Wc[64][128];   // W1 chunk [k][col]
  __shared__ float Ht[128][20];   // normalized h transposed [col][row]
  const int t = threadIdx.x;
  const int row0 = blockIdx.x << 4;
  const int rg = t >> 6;          // wave id = row group (4 rows each)
  const int r0 = rg << 2;
  const int cg = t & 63;          // 64 col groups x 2 cols
  const int c0 = cg << 1;
  const int lr = t >> 4, lkc = (t & 15) << 2;
  float acc[4][2] = {{0,0},{0,0},{0,0},{0,0}};

  for (int k0 = 0; k0 < 1024; k0 += 64) {
    __syncthreads();
    {  // A chunk: 16 rows x 64 k (transposed store)
      const float4 av = *(const float4*)&X[(size_t)(row0 + lr) * 1024 + k0 + lkc];
      At[lkc + 0][lr] = av.x; At[lkc + 1][lr] = av.y;
      At[lkc + 2][lr] = av.z; At[lkc + 3][lr] = av.w;
    }
    {  // W1 chunk: 64 x 128 linear copy
      const float4* wsrc = (const float4*)&W1[(size_t)k0 * 128];
      float4* wdst = (float4*)&Wc[0][0];
#pragma unroll
      for (int i = 0; i < 8; i++) wdst[t + (i << 8)] = wsrc[t + (i << 8)];
    }
    __syncthreads();
#pragma unroll
    for (int kk = 0; kk < 64; kk++) {
      const float4 a = *(const float4*)&At[kk][r0];   // broadcast within wave
      const float2 w = *(const float2*)&Wc[kk][c0];
      acc[0][0] = fmaf(a.x, w.x, acc[0][0]); acc[0][1] = fmaf(a.x, w.y, acc[0][1]);
      acc[1][0] = fmaf(a.y, w.x, acc[1][0]); acc[1][1] = fmaf(a.y, w.y, acc[1][1]);
      acc[2][0] = fmaf(a.z, w.x, acc[2][0]); acc[2][1] = fmaf(a.z, w.y, acc[2][1]);
      acc[3][0] = fmaf(a.w, w.x, acc[3][0]); acc[3][1] = fmaf(a.w, w.y, acc[3][1]);
    }
  }
  const float b1a = B1[c0], b1b = B1[c0 + 1];
  float h[4][2], s1[4], s2[4];
#pragma unroll
  for (int i = 0; i < 4; i++) {
    h[i][0] = fmaxf(acc[i][0] + b1a, 0.f);
    h[i][1] = fmaxf(acc[i][1] + b1b, 0.f);
    s1[i] = h[i][0] + h[i][1];
    s2[i] = h[i][0] * h[i][0] + h[i][1] * h[i][1];
  }
#pragma unroll
  for (int m = 32; m >= 1; m >>= 1) {
#pragma unroll
    for (int i = 0; i < 4; i++) { s1[i] += __shfl_xor(s1[i], m); s2[i] += __shfl_xor(s2[i], m); }
  }
  const float ga = G1[c0], gb = G1[c0 + 1], ba = Bn1[c0], bb = Bn1[c0 + 1];
#pragma unroll
  for (int i = 0; i < 4; i++) {
    const float mean = s1[i] * (1.f / 128.f);
    const float var  = s2[i] * (1.f / 128.f) - mean * mean;
    const float rs = rsqrtf(var + LN_EPS);
    Ht[c0 + 0][r0 + i] = (h[i][0] - mean) * rs * ga + ba;
    Ht[c0 + 1][r0 + i] = (h[i][1] - mean) * rs * gb + bb;
  }
  __syncthreads();
  float za[4] = {0, 0, 0, 0};
  for (int k = 0; k < 128; k++) {
    const float4 hv = *(const float4*)&Ht[k][r0];
    const float wv = W2[(k << 6) + cg];
    za[0] = fmaf(hv.x, wv, za[0]); za[1] = fmaf(hv.y, wv, za[1]);
    za[2] = fmaf(hv.z, wv, za[2]); za[3] = fmaf(hv.w, wv, za[3]);
  }
  const float b2v = B2[cg];
#pragma unroll
  for (int i = 0; i < 4; i++)
    Z[(size_t)(row0 + r0 + i) * 64 + cg] = za[i] + b2v;
}

// ---------- K2: distances + partial argmin ----------
// score = |c|^2 - 2 z.c  (|z|^2 constant per row, drops from argmin)
// LDS-BW-bound analysis (R6): raise FMA per LDS byte. 8 rows x 4 codes per
// lane: 32 FMA per 16B distinct-address Ct read; Zt reads are broadcast.
// grid 512 = 128 row-blocks x 4 code-quarters; block: 64 rows x 2048 codes,
// 16 chunks of 128 codes. Pads mod-32 = 4 (132/68), as in R3's low-conflict
// config. Per-(row,code) k-accumulation order unchanged -> indices bit-exact.
__global__ __launch_bounds__(256) void k2_dist(const float* __restrict__ Z,
                                               const float* __restrict__ CB,
                                               const float* __restrict__ C2,
                                               float* __restrict__ Pval,
                                               int* __restrict__ Pidx) {
  __shared__ float Zt[64][68];     // z tile transposed [k][row]  (17.4 KB)
  __shared__ float Ct[64][132];    // codebook chunk transposed   (33.8 KB)
  const int t = threadIdx.x;
  const int lane = t & 63, wave = t >> 6;
  const int rowblk = blockIdx.x >> 2, quarter = blockIdx.x & 3;
  const int row0 = rowblk << 6;       // 64 rows
  const int code0 = quarter << 11;    // 2048 codes per quarter
  const int r0 = (t >> 5) << 3;       // 8 row-groups x 8 rows
  const int c0 = (lane & 31) << 2;    // 32 code-groups x 4 codes

  // stage Zt: 64 rows x 64 k, transposed (once per block)
#pragma unroll
  for (int i = 0; i < 4; i++) {
    const int f = t + (i << 8);
    const int r = f >> 4, kc = (f & 15) << 2;
    const float4 v = *(const float4*)&Z[(size_t)(row0 + r) * 64 + kc];
    Zt[kc + 0][r] = v.x; Zt[kc + 1][r] = v.y;
    Zt[kc + 2][r] = v.z; Zt[kc + 3][r] = v.w;
  }

  // staging assignment per (cr in 0..1, r in 0..3):
  //   code  = cr*64 + wave*16 + (lane>>2)   [16 consecutive codes per wave]
  //   kbase = 4*(lane&3) + 16*r             [4 lanes cover one 64B line]
  // global: fully line-coalesced; transposed LDS store: 2-way (free)
  const int wq = (wave << 4) + (lane >> 2);   // 0..63
  const int kb = (lane & 3) << 2;             // 0,4,8,12
  float4 st[8];
#define K2_PF(cr, r) \
  st[(cr) * 4 + (r)] = *(const float4*)&CB[(size_t)(code0 + chunk * 128 + (cr) * 64 + wq) * 64 + kb + 16 * (r)];
#define K2_WR(cr, r) { \
    const float4 v = st[(cr) * 4 + (r)]; \
    const int k2r = kb + 16 * (r); const int col = (cr) * 64 + wq; \
    Ct[k2r + 0][col] = v.x; Ct[k2r + 1][col] = v.y; \
    Ct[k2r + 2][col] = v.z; Ct[k2r + 3][col] = v.w; }

  {  // prefetch chunk 0
    const int chunk = 0;
    K2_PF(0, 0) K2_PF(0, 1) K2_PF(0, 2) K2_PF(0, 3)
    K2_PF(1, 0) K2_PF(1, 1) K2_PF(1, 2) K2_PF(1, 3)
  }
  __syncthreads();   // Zt visible; Ct has no readers yet

  float minv[8];
  int   mini[8];
#pragma unroll
  for (int i = 0; i < 8; i++) { minv[i] = 3.4e38f; mini[i] = 0; }

  for (int c = 0; c < 16; c++) {
    // write staged regs -> Ct (vmcnt wait for st happens here)
    K2_WR(0, 0) K2_WR(0, 1) K2_WR(0, 2) K2_WR(0, 3)
    K2_WR(1, 0) K2_WR(1, 1) K2_WR(1, 2) K2_WR(1, 3)
    __syncthreads();
    if (c + 1 < 16) {   // prefetch next chunk (overlaps compute below)
      const int chunk = c + 1;
      K2_PF(0, 0) K2_PF(0, 1) K2_PF(0, 2) K2_PF(0, 3)
      K2_PF(1, 0) K2_PF(1, 1) K2_PF(1, 2) K2_PF(1, 3)
    }
    float acc[8][4];
#pragma unroll
    for (int i = 0; i < 8; i++)
#pragma unroll
      for (int j = 0; j < 4; j++) acc[i][j] = 0.f;
#pragma unroll 2
    for (int k = 0; k < 64; k++) {
      const float4 za = *(const float4*)&Zt[k][r0];       // broadcast (half-wave)
      const float4 zb = *(const float4*)&Zt[k][r0 + 4];   // broadcast (half-wave)
      const float4 cv = *(const float4*)&Ct[k][c0];       // distinct 16B/lane
      const float zr[8] = {za.x, za.y, za.z, za.w, zb.x, zb.y, zb.z, zb.w};
      const float cc[4] = {cv.x, cv.y, cv.z, cv.w};
#pragma unroll
      for (int i = 0; i < 8; i++)
#pragma unroll
        for (int j = 0; j < 4; j++)
          acc[i][j] = fmaf(zr[i], cc[j], acc[i][j]);
    }
    // per-chunk min update
    const int codeb = code0 + (c << 7) + c0;
    const float4 c2v = *(const float4*)&C2[codeb];
    const float c2a[4] = {c2v.x, c2v.y, c2v.z, c2v.w};
#pragma unroll
    for (int i = 0; i < 8; i++)
#pragma unroll
      for (int j = 0; j < 4; j++) {
        const float s = fmaf(-2.f, acc[i][j], c2a[j]);
        if (s < minv[i]) { minv[i] = s; mini[i] = codeb + j; }
      }
    __syncthreads();   // all reads of Ct done before next WR
  }
#undef K2_PF
#undef K2_WR
  // argmin reduce across the 32 lanes of each half (xor<=16 stays in half)
#pragma unroll
  for (int m = 16; m >= 1; m >>= 1) {
#pragma unroll
    for (int i = 0; i < 8; i++) {
      const float ov = __shfl_xor(minv[i], m);
      const int   oi = __shfl_xor(mini[i], m);
      if (ov < minv[i] || (ov == minv[i] && oi < mini[i])) { minv[i] = ov; mini[i] = oi; }
    }
  }
  if ((lane & 31) == 0) {
#pragma unroll
    for (int i = 0; i < 8; i++) {
      const int r = row0 + r0 + i;
      Pval[r * 4 + quarter] = minv[i];
      Pidx[r * 4 + quarter] = mini[i];
    }
  }
}

// ---------- K2m: merge the four code-quarter partials ----------
__global__ __launch_bounds__(256) void k2_merge(const float* __restrict__ Pval,
                                                const int* __restrict__ Pidx,
                                                int* __restrict__ IDX,
                                                float* __restrict__ outIdx,
                                                float* __restrict__ usage) {
  const int r = blockIdx.x * 256 + threadIdx.x;   // 8192 threads
  const float4 v = *(const float4*)&Pval[r * 4];
  const int4   i = *(const int4*)&Pidx[r * 4];
  float bv = v.x; int bi = i.x;                    // quarter-major order keeps
  if (v.y < bv) { bv = v.y; bi = i.y; }            // first-occurrence tie-break
  if (v.z < bv) { bv = v.z; bi = i.z; }
  if (v.w < bv) { bv = v.w; bi = i.w; }
  IDX[r] = bi;
  outIdx[r] = (float)bi;
  atomicAdd(&usage[bi], 1.0f);
}

// ---------- transpose + cast fp32 [R][C] -> bf16 [C][R] ----------
__global__ __launch_bounds__(256) void k_tcast(const float* __restrict__ src,
                                               unsigned short* __restrict__ dst,
                                               int R, int C) {
  __shared__ float T[32][33];
  const int tilesC = C >> 5;
  const int bx = blockIdx.x;
  const int tr = bx / tilesC, tc = bx - tr * tilesC;
  const int t = threadIdx.x;
  {
    const int r = t >> 3, c4 = (t & 7) << 2;
    const float4 v = *(const float4*)&src[(size_t)(tr * 32 + r) * C + tc * 32 + c4];
    T[r][c4] = v.x; T[r][c4 + 1] = v.y; T[r][c4 + 2] = v.z; T[r][c4 + 3] = v.w;
  }
  __syncthreads();
  const int c = t >> 3, r4 = (t & 7) << 2;
  ushort4 o;
  o.x = f2bf(T[r4 + 0][c]); o.y = f2bf(T[r4 + 1][c]);
  o.z = f2bf(T[r4 + 2][c]); o.w = f2bf(T[r4 + 3][c]);
  *(ushort4*)&dst[(size_t)(tc * 32 + c) * R + tr * 32 + r4] = o;
}

// ---------- K3: gather codebook rows by index, cast to bf16 ----------
__global__ __launch_bounds__(256) void k3_gather(const float* __restrict__ CB,
                                                 const int* __restrict__ IDX,
                                                 unsigned short* __restrict__ SEL) {
  const int g = blockIdx.x * 256 + threadIdx.x;  // 131072 threads
  const int row = g >> 4, c4 = (g & 15) << 2;
  const int code = IDX[row];
  const float4 v = *(const float4*)&CB[(size_t)code * 64 + c4];
  ushort4 o;
  o.x = f2bf(v.x); o.y = f2bf(v.y); o.z = f2bf(v.z); o.w = f2bf(v.w);
  *(ushort4*)&SEL[(size_t)row * 64 + c4] = o;
}

// ---------- K4: h1 = relu(sel @ rec_w1 + b1), bf16 out; M=8192 N=2048 K=64 ----------
__global__ __launch_bounds__(256) void k4_rec1(const unsigned short* __restrict__ A,
                                               const unsigned short* __restrict__ Bt,
                                               const float* __restrict__ bias,
                                               unsigned short* __restrict__ H) {
  __shared__ __align__(16) unsigned short As[128 * 64];
  __shared__ __align__(16) unsigned short Bs[128 * 64];
  const int t = threadIdx.x;
  const int wave = t >> 6, lane = t & 63;
  const int bx = blockIdx.x;
  const int tm = bx >> 4, tn = bx & 15;
  const int m0 = tm << 7, n0 = tn << 7;
  const int wm = wave >> 1, wn = wave & 1;
  const int ln15 = lane & 15, lk = (lane >> 4) << 3;
  stage_tile(A + (size_t)m0 * 64, 64, As, wave, lane);
  stage_tile(Bt + (size_t)n0 * 64, 64, Bs, wave, lane);
  asm volatile("s_waitcnt vmcnt(0)" ::: "memory");
  __syncthreads();
  f32x4 acc[4][4];
#pragma unroll
  for (int i = 0; i < 4; i++)
#pragma unroll
    for (int j = 0; j < 4; j++) acc[i][j] = (f32x4){0.f, 0.f, 0.f, 0.f};
#pragma unroll
  for (int ks = 0; ks < 2; ks++) {
    short8 a[4], b[4];
#pragma unroll
    for (int i = 0; i < 4; i++)
      a[i] = *(const short8*)&As[(wm * 64 + i * 16 + ln15) * 64 + ks * 32 + lk];
#pragma unroll
    for (int j = 0; j < 4; j++)
      b[j] = *(const short8*)&Bs[(wn * 64 + j * 16 + ln15) * 64 + ks * 32 + lk];
#pragma unroll
    for (int i = 0; i < 4; i++)
#pragma unroll
      for (int j = 0; j < 4; j++)
        acc[i][j] = __builtin_amdgcn_mfma_f32_16x16x32_bf16(a[i], b[j], acc[i][j], 0, 0, 0);
  }
  const int l4 = (lane >> 4) << 2;
#pragma unroll
  for (int j = 0; j < 4; j++) {
    const int col = n0 + wn * 64 + j * 16 + ln15;
    const float bv = bias[col];
#pragma unroll
    for (int i = 0; i < 4; i++) {
      const int row = m0 + wm * 64 + i * 16 + l4;
#pragma unroll
      for (int r = 0; r < 4; r++)
        H[(size_t)(row + r) * 2048 + col] = f2bf(fmaxf(acc[i][j][r] + bv, 0.f));
    }
  }
}

// ---------- K5: in-place LayerNorm(2048) on bf16 rows ----------
__global__ __launch_bounds__(256) void k5_ln(unsigned short* __restrict__ H,
                                             const float* __restrict__ G,
                                             const float* __restrict__ B) {
  const int row = blockIdx.x, t = threadIdx.x;
  unsigned short* p = H + (size_t)row * 2048 + t * 8;
  const uint4 raw = *(const uint4*)p;
  float v[8];
  v[0] = bf2f(raw.x & 0xffffu); v[1] = bf2f(raw.x >> 16);
  v[2] = bf2f(raw.y & 0xffffu); v[3] = bf2f(raw.y >> 16);
  v[4] = bf2f(raw.z & 0xffffu); v[5] = bf2f(raw.z >> 16);
  v[6] = bf2f(raw.w & 0xffffu); v[7] = bf2f(raw.w >> 16);
  float s1 = 0.f, s2 = 0.f;
#pragma unroll
  for (int i = 0; i < 8; i++) { s1 += v[i]; s2 = fmaf(v[i], v[i], s2); }
#pragma unroll
  for (int m = 32; m >= 1; m >>= 1) { s1 += __shfl_xor(s1, m); s2 += __shfl_xor(s2, m); }
  __shared__ float red[8];
  const int lane = t & 63, wv = t >> 6;
  if (lane == 0) { red[wv] = s1; red[4 + wv] = s2; }
  __syncthreads();
  s1 = red[0] + red[1] + red[2] + red[3];
  s2 = red[4] + red[5] + red[6] + red[7];
  const float mean = s1 * (1.f / 2048.f);
  const float var  = s2 * (1.f / 2048.f) - mean * mean;
  const float rs = rsqrtf(var + LN_EPS);
  const int c = t * 8;
  unsigned int w0, w1, w2, w3;
  {
    const float o0 = (v[0] - mean) * rs * G[c + 0] + B[c + 0];
    const float o1 = (v[1] - mean) * rs * G[c + 1] + B[c + 1];
    w0 = (unsigned int)f2bf(o0) | ((unsigned int)f2bf(o1) << 16);
  }
  {
    const float o0 = (v[2] - mean) * rs * G[c + 2] + B[c + 2];
    const float o1 = (v[3] - mean) * rs * G[c + 3] + B[c + 3];
    w1 = (unsigned int)f2bf(o0) | ((unsigned int)f2bf(o1) << 16);
  }
  {
    const float o0 = (v[4] - mean) * rs * G[c + 4] + B[c + 4];
    const float o1 = (v[5] - mean) * rs * G[c + 5] + B[c + 5];
    w2 = (unsigned int)f2bf(o0) | ((unsigned int)f2bf(o1) << 16);
  }
  {
    const float o0 = (v[6] - mean) * rs * G[c + 6] + B[c + 6];
    const float o1 = (v[7] - mean) * rs * G[c + 7] + B[c + 7];
    w3 = (unsigned int)f2bf(o0) | ((unsigned int)f2bf(o1) << 16);
  }
  uint4 outw; outw.x = w0; outw.y = w1; outw.z = w2; outw.w = w3;
  *(uint4*)p = outw;
}

// ---------- K6: recon = r @ rec_w2 + b2; M=8192 N=1024 K=2048, fp32 out ----------
__global__ __launch_bounds__(256) void k6_rec2(const unsigned short* __restrict__ A,
                                               const unsigned short* __restrict__ Bt,
                                               const float* __restrict__ bias,
                                               float* __restrict__ C) {
  __shared__ __align__(16) unsigned short As[128 * 64];
  __shared__ __align__(16) unsigned short Bs[128 * 64];
  const int t = threadIdx.x;
  const int wave = t >> 6, lane = t & 63;
  const int bx = blockIdx.x;
  const int tm = bx >> 3, tn = bx & 7;
  const int m0 = tm << 7, n0 = tn << 7;
  const int wm = wave >> 1, wn = wave & 1;
  const int ln15 = lane & 15, lk = (lane >> 4) << 3;
  f32x4 acc[4][4];
#pragma unroll
  for (int i = 0; i < 4; i++)
#pragma unroll
    for (int j = 0; j < 4; j++) acc[i][j] = (f32x4){0.f, 0.f, 0.f, 0.f};

  for (int k0 = 0; k0 < 2048; k0 += 64) {
    __syncthreads();
    stage_tile(A + (size_t)m0 * 2048 + k0, 2048, As, wave, lane);
    stage_tile(Bt + (size_t)n0 * 2048 + k0, 2048, Bs, wave, lane);
    asm volatile("s_waitcnt vmcnt(0)" ::: "memory");
    __syncthreads();
#pragma unroll
    for (int ks = 0; ks < 2; ks++) {
      short8 a[4], b[4];
#pragma unroll
      for (int i = 0; i < 4; i++)
        a[i] = *(const short8*)&As[(wm * 64 + i * 16 + ln15) * 64 + ks * 32 + lk];
#pragma unroll
      for (int j = 0; j < 4; j++)
        b[j] = *(const short8*)&Bs[(wn * 64 + j * 16 + ln15) * 64 + ks * 32 + lk];
#pragma unroll
      for (int i = 0; i < 4; i++)
#pragma unroll
        for (int j = 0; j < 4; j++)
          acc[i][j] = __builtin_amdgcn_mfma_f32_16x16x32_bf16(a[i], b[j], acc[i][j], 0, 0, 0);
    }
  }
  const int l4 = (lane >> 4) << 2;
#pragma unroll
  for (int j = 0; j < 4; j++) {
    const int col = n0 + wn * 64 + j * 16 + ln15;
    const float bv = bias[col];
#pragma unroll
    for (int i = 0; i < 4; i++) {
      const int row = m0 + wm * 64 + i * 16 + l4;
#pragma unroll
      for (int r = 0; r < 4; r++)
        C[(size_t)(row + r) * 1024 + col] = acc[i][j][r] + bv;
    }
  }
}

extern "C" void kernel_launch(void* const* d_in, const int* in_sizes, int n_in,
                              void* d_out, int out_size, void* d_ws, size_t ws_size,
                              hipStream_t stream) {
  (void)in_sizes; (void)n_in; (void)out_size; (void)ws_size;
  const float* features = (const float*)d_in[0];
  const float* codebook = (const float*)d_in[1];
  const float* proj_w1  = (const float*)d_in[2];
  const float* proj_b1  = (const float*)d_in[3];
  const float* ln1_g    = (const float*)d_in[4];
  const float* ln1_b    = (const float*)d_in[5];
  const float* proj_w2  = (const float*)d_in[6];
  const float* proj_b2  = (const float*)d_in[7];
  const float* rec_w1   = (const float*)d_in[8];
  const float* rec_b1   = (const float*)d_in[9];
  const float* ln2_g    = (const float*)d_in[10];
  const float* ln2_b    = (const float*)d_in[11];
  const float* rec_w2   = (const float*)d_in[12];
  const float* rec_b2   = (const float*)d_in[13];

  float* out_recon = (float*)d_out;                    // [8192][1024]
  float* out_idx   = out_recon + (size_t)8192 * 1024;  // [8192] (as float)
  float* out_usage = out_idx + 8192;                   // [8192]

  char* ws = (char*)d_ws;
  float*          c2  = (float*)(ws);                       // 32 KB
  int*            idx = (int*)(ws + 32768);                 // 32 KB
  float*          z   = (float*)(ws + 65536);               // 2 MB
  unsigned short* sel = (unsigned short*)(ws + 2162688);    // 1 MB  bf16
  unsigned short* w1t = (unsigned short*)(ws + 3211264);    // 256 KB bf16 [2048][64]
  unsigned short* w2t = (unsigned short*)(ws + 3473408);    // 4 MB  bf16 [1024][2048]
  unsigned short* h1  = (unsigned short*)(ws + 7667712);    // 32 MB bf16 [8192][2048]
  // argmin partials overlap sel's region (consumed by k2_merge before k3 writes sel)
  float* pval = (float*)(ws + 2162688);                     // 128 KB [8192][4]
  int*   pidx = (int*)(ws + 2162688 + 131072);              // 128 KB [8192][4]

  k0_c2_zero<<<512, 256, 0, stream>>>(codebook, c2, out_usage);
  k1_encode <<<512, 256, 0, stream>>>(features, proj_w1, proj_b1, ln1_g, ln1_b,
                                      proj_w2, proj_b2, z);
  k2_dist   <<<512, 256, 0, stream>>>(z, codebook, c2, pval, pidx);
  k2_merge  <<<32, 256, 0, stream>>>(pval, pidx, idx, out_idx, out_usage);
  k_tcast   <<<128, 256, 0, stream>>>(rec_w1, w1t, 64, 2048);    // -> [2048][64]
  k_tcast   <<<2048, 256, 0, stream>>>(rec_w2, w2t, 2048, 1024); // -> [1024][2048]
  k3_gather <<<512, 256, 0, stream>>>(codebook, idx, sel);
  k4_rec1   <<<1024, 256, 0, stream>>>(sel, w1t, rec_b1, h1);
  k5_ln     <<<8192, 256, 0, stream>>>(h1, ln2_g, ln2_b);
  k6_rec2   <<<512, 256, 0, stream>>>(h1, w2t, rec_b2, out_recon);
}